// Round 5
// baseline (95.340 us; speedup 1.0000x reference)
//
#include <hip/hip_runtime.h>
#include <math.h>

#define MAXR 100.0f
// Fixed shapes: B=4, C=64, H=64, W=64; conv (2,64,3,3) OIHW, SAME.

__device__ __forceinline__ float tanh_fast(float s) {
    float as = fabsf(s);
    float e2 = __expf(-2.0f * as);
    float t  = (1.0f - e2) * __builtin_amdgcn_rcpf(1.0f + e2);
    return copysignf(t, s);
}

// ---- Kernel 1: 3x3 conv (64->2) + 100*tanh -> alpha, beta. One block per (b,h) row.
__global__ __launch_bounds__(256) void conv_ab(const float* __restrict__ x,
                                               const float* __restrict__ w,
                                               const float* __restrict__ bias,
                                               float* __restrict__ alpha,
                                               float* __restrict__ beta) {
    __shared__ float xs[64 * 3 * 64];   // [c][r][w]  48 KB
    __shared__ float wl[1152];
    __shared__ float red[4][2][64];

    int row = blockIdx.x;               // b*64 + h
    int b = row >> 6, h = row & 63;
    int tid = threadIdx.x;
    int lane = tid & 63, g = tid >> 6;
    int l4 = lane & 15, quad = lane >> 4;

    for (int e = tid; e < 1152; e += 256) wl[e] = w[e];

    const float* xb = x + b * 262144;
    for (int pair = g * 4 + quad; pair < 192; pair += 16) {
        int r = pair >> 6, c = pair & 63;
        int hh = h + r - 1;
        float4 v = make_float4(0.f, 0.f, 0.f, 0.f);
        if (hh >= 0 && hh < 64)
            v = *(const float4*)(xb + c * 4096 + hh * 64 + l4 * 4);
        *(float4*)(xs + c * 192 + r * 64 + l4 * 4) = v;
    }
    __syncthreads();

    float a0 = 0.f, a1 = 0.f;
    bool mL = (lane >= 1), mR = (lane <= 62);
    for (int cc = 0; cc < 16; ++cc) {
        int c = (g << 4) + cc;
        const float* xc = xs + c * 192;
        const float* w0 = wl + c * 9;
        const float* w1 = wl + 576 + c * 9;
        #pragma unroll
        for (int r = 0; r < 3; ++r) {
            float xm = mL ? xc[r * 64 + lane - 1] : 0.f;
            float x0 = xc[r * 64 + lane];
            float xp = mR ? xc[r * 64 + lane + 1] : 0.f;
            a0 = fmaf(xm, w0[r * 3 + 0], a0);
            a0 = fmaf(x0, w0[r * 3 + 1], a0);
            a0 = fmaf(xp, w0[r * 3 + 2], a0);
            a1 = fmaf(xm, w1[r * 3 + 0], a1);
            a1 = fmaf(x0, w1[r * 3 + 1], a1);
            a1 = fmaf(xp, w1[r * 3 + 2], a1);
        }
    }
    red[g][0][lane] = a0;
    red[g][1][lane] = a1;
    __syncthreads();

    if (g < 2) {
        float s = red[0][g][lane] + red[1][g][lane] + red[2][g][lane] + red[3][g][lane];
        s += bias[g];
        (g == 0 ? alpha : beta)[row * 64 + lane] = MAXR * tanh_fast(s);
    }
}

// ---- Kernel 2: per-pixel pairwise soft-abs + softmax + weighted sum.
// 4096 blocks x 256 (4 waves); ONE pixel per wave; lane = channel j.
// Minimal LDS (4x68 transposed columns), 4 explicit independent chains.
__global__ __launch_bounds__(256) void dsf_main(const float* __restrict__ x,
                                                const float* __restrict__ alpha_g,
                                                const float* __restrict__ beta_g,
                                                float* __restrict__ out) {
    __shared__ float xst[4 * 68];       // [pixel][c]
    const int tid = threadIdx.x, lane = tid & 63, wave = tid >> 6;
    const int p0 = blockIdx.x * 4;      // 4 consecutive-w pixels, same (b,h)
    const int b = p0 >> 12;
    const float* xb = x + b * 262144 + (p0 & 4095);

    {   // stage 4 px x 64 c: one load/thread, 16B runs in global
        int c = tid >> 2, wl = tid & 3;
        xst[wl * 68 + c] = xb[c * 4096 + wl];
    }
    __syncthreads();

    const int p = p0 + wave;
    const float al = alpha_g[p];        // wave-uniform broadcast load
    const float be = beta_g[p];
    const float aa = fabsf(al);
    const float n2aa = -2.0f * aa;      // tanh(z)=(1-e^-2z)/(1+e^-2z), z=aa*|d|

    const float* xr = xst + wave * 68;
    const float xj = xr[lane];

    float A0 = 0.f, A1 = 0.f, A2 = 0.f, A3 = 0.f;
    #pragma unroll 4
    for (int i = 0; i < 16; ++i) {
        float xi0 = xr[i];
        float xi1 = xr[i + 16];
        float xi2 = xr[i + 32];
        float xi3 = xr[i + 48];
        float d0 = fmaf(be, xi0, -xj); float a0 = fabsf(d0);
        float d1 = fmaf(be, xi1, -xj); float a1 = fabsf(d1);
        float d2 = fmaf(be, xi2, -xj); float a2 = fabsf(d2);
        float d3 = fmaf(be, xi3, -xj); float a3 = fabsf(d3);
        float e0 = __expf(n2aa * a0);
        float e1 = __expf(n2aa * a1);
        float e2 = __expf(n2aa * a2);
        float e3 = __expf(n2aa * a3);
        float t0 = (1.f - e0) * __builtin_amdgcn_rcpf(1.f + e0);
        float t1 = (1.f - e1) * __builtin_amdgcn_rcpf(1.f + e1);
        float t2 = (1.f - e2) * __builtin_amdgcn_rcpf(1.f + e2);
        float t3 = (1.f - e3) * __builtin_amdgcn_rcpf(1.f + e3);
        A0 = fmaf(a0, t0, A0);
        A1 = fmaf(a1, t1, A1);
        A2 = fmaf(a2, t2, A2);
        A3 = fmaf(a3, t3, A3);
    }
    float A = (A0 + A1) + (A2 + A3);

    // logits: g_j = max(-A*|alpha|/64, -100)  (sign(alpha) cancels exactly)
    float gl = fmaxf(-A * aa * (1.0f / 64.0f), -MAXR);

    float gm = gl;
    #pragma unroll
    for (int off = 32; off; off >>= 1) gm = fmaxf(gm, __shfl_xor(gm, off, 64));
    float ew  = __expf(gl - gm);
    float den = ew, num = xj * ew;
    #pragma unroll
    for (int off = 32; off; off >>= 1) {
        den += __shfl_xor(den, off, 64);
        num += __shfl_xor(num, off, 64);
    }
    if (lane == 0) out[p] = num * __builtin_amdgcn_rcpf(den);
}

extern "C" void kernel_launch(void* const* d_in, const int* in_sizes, int n_in,
                              void* d_out, int out_size, void* d_ws, size_t ws_size,
                              hipStream_t stream) {
    const float* x      = (const float*)d_in[0];   // (4,64,64,64)
    const float* conv_w = (const float*)d_in[1];   // (2,64,3,3)
    const float* conv_b = (const float*)d_in[2];   // (2,)
    float* out   = (float*)d_out;                  // (4,1,64,64)
    float* alpha = (float*)d_ws;                   // 16384 floats
    float* beta  = alpha + 16384;

    conv_ab<<<256, 256, 0, stream>>>(x, conv_w, conv_b, alpha, beta);
    dsf_main<<<4096, 256, 0, stream>>>(x, alpha, beta, out);
}

// Round 6
// 92.421 us; speedup vs baseline: 1.0316x; 1.0316x over previous
//
#include <hip/hip_runtime.h>
#include <math.h>

#define MAXR 100.0f
#define LOG2E 1.4426950408889634f
// Fixed shapes: B=4, C=64, H=64, W=64; conv (2,64,3,3) OIHW, SAME.

__device__ __forceinline__ float bcast_lane(float v, int i) {
    return __int_as_float(__builtin_amdgcn_readlane(__float_as_int(v), i));
}
__device__ __forceinline__ float exp2_fast(float x) { return __builtin_amdgcn_exp2f(x); }
__device__ __forceinline__ float rcp_fast(float x)  { return __builtin_amdgcn_rcpf(x); }

__device__ __forceinline__ float tanh_fast(float s) {
    // tanh(s) = sign(s) * (1 - 2/(e^{2|s|}+1)); E=inf -> t=1 exactly
    float E = exp2_fast(2.0f * LOG2E * fabsf(s));
    float t = fmaf(-2.0f, rcp_fast(E + 1.0f), 1.0f);
    return copysignf(t, s);
}

// ---- Kernel A: 3x3 conv (64->2) + 100*tanh -> alpha,beta; ALSO writes xT[pixel][c].
// One block per (b,h) row; lane = channel; wave g owns pixels g*16..g*16+15.
__global__ __launch_bounds__(256) void prep(const float* __restrict__ x,
                                            const float* __restrict__ wg,
                                            const float* __restrict__ bias,
                                            float* __restrict__ xT,
                                            float* __restrict__ alpha,
                                            float* __restrict__ beta) {
    __shared__ float xs[64 * 195];   // [c][r][w], r-stride 65, c-stride 195 (odd: conflict-free)
    __shared__ float wl[1152];

    const int row = blockIdx.x;      // b*64 + h
    const int b = row >> 6, h = row & 63;
    const int tid = threadIdx.x, lane = tid & 63, g = tid >> 6;
    const int l4 = lane & 15, quad = lane >> 4;

    for (int e = tid; e < 1152; e += 256) wl[e] = wg[e];

    const float* xb = x + b * 262144;
    for (int pr = g * 4 + quad; pr < 192; pr += 16) {
        int r = pr >> 6, c = pr & 63;
        int hh = h + r - 1;
        float4 v = make_float4(0.f, 0.f, 0.f, 0.f);
        if (hh >= 0 && hh < 64)
            v = *(const float4*)(xb + c * 4096 + hh * 64 + l4 * 4);
        *(float4*)(xs + c * 195 + r * 65 + l4 * 4) = v;
    }
    __syncthreads();

    // transposed center row -> xT[pixel][c]  (coalesced 256B stores; lane = c)
    float* xTrow = xT + row * 4096;
    #pragma unroll
    for (int wi = 0; wi < 16; ++wi) {
        int wp = g * 16 + wi;
        xTrow[wp * 64 + lane] = xs[lane * 195 + 65 + wp];   // stride 195: conflict-free
    }

    // conv: lane = channel, weights in registers, butterfly-sum per pixel
    float wr0[9], wr1[9];
    #pragma unroll
    for (int k = 0; k < 9; ++k) {
        wr0[k] = wl[lane * 9 + k];
        wr1[k] = wl[576 + lane * 9 + k];
    }
    const float b0 = bias[0], b1 = bias[1];
    const float* xc = xs + lane * 195;

    for (int wi = 0; wi < 16; ++wi) {
        int wp = g * 16 + wi;
        bool mL = (wp >= 1), mR = (wp <= 62);
        float a0 = 0.f, a1 = 0.f;
        #pragma unroll
        for (int r = 0; r < 3; ++r) {
            float xm = mL ? xc[r * 65 + wp - 1] : 0.f;
            float x0 = xc[r * 65 + wp];
            float xp = mR ? xc[r * 65 + wp + 1] : 0.f;
            a0 = fmaf(xm, wr0[r * 3 + 0], a0);
            a0 = fmaf(x0, wr0[r * 3 + 1], a0);
            a0 = fmaf(xp, wr0[r * 3 + 2], a0);
            a1 = fmaf(xm, wr1[r * 3 + 0], a1);
            a1 = fmaf(x0, wr1[r * 3 + 1], a1);
            a1 = fmaf(xp, wr1[r * 3 + 2], a1);
        }
        #pragma unroll
        for (int off = 32; off; off >>= 1) {
            a0 += __shfl_xor(a0, off, 64);
            a1 += __shfl_xor(a1, off, 64);
        }
        if (lane == 0) {
            alpha[row * 64 + wp] = MAXR * tanh_fast(a0 + b0);
            beta [row * 64 + wp] = MAXR * tanh_fast(a1 + b1);
        }
    }
}

// ---- Kernel B: pairwise soft-abs + softmax + weighted sum. NO __shared__, no barrier.
// 4096 blocks x 256 (4 waves); one pixel per wave; lane = channel j.
// x_i broadcast via v_readlane (VALU pipe) from the coalesced xT row in registers.
__global__ __launch_bounds__(256) void pairwise(const float* __restrict__ xT,
                                                const float* __restrict__ alpha_g,
                                                const float* __restrict__ beta_g,
                                                float* __restrict__ out) {
    const int tid = threadIdx.x, lane = tid & 63, wave = tid >> 6;
    const int p = blockIdx.x * 4 + wave;

    const float xj = xT[p * 64 + lane];     // coalesced 256B per wave
    const float al = alpha_g[p];            // wave-uniform
    const float be = beta_g[p];
    const float aa = fabsf(al);
    const float c2 = 2.0f * LOG2E * aa;     // t = 1 - 2/(2^(c2*|d|)+1)

    float A0 = 0.f, A1 = 0.f, A2 = 0.f, A3 = 0.f;
    #pragma unroll
    for (int i = 0; i < 64; i += 4) {
        float s0 = bcast_lane(xj, i);
        float s1 = bcast_lane(xj, i + 1);
        float s2 = bcast_lane(xj, i + 2);
        float s3 = bcast_lane(xj, i + 3);
        float d0 = fmaf(be, s0, -xj);
        float d1 = fmaf(be, s1, -xj);
        float d2 = fmaf(be, s2, -xj);
        float d3 = fmaf(be, s3, -xj);
        float E0 = exp2_fast(c2 * fabsf(d0));
        float E1 = exp2_fast(c2 * fabsf(d1));
        float E2 = exp2_fast(c2 * fabsf(d2));
        float E3 = exp2_fast(c2 * fabsf(d3));
        float r0 = rcp_fast(E0 + 1.f);
        float r1 = rcp_fast(E1 + 1.f);
        float r2 = rcp_fast(E2 + 1.f);
        float r3 = rcp_fast(E3 + 1.f);
        float u0 = fmaf(-2.f, r0, 1.f);
        float u1 = fmaf(-2.f, r1, 1.f);
        float u2 = fmaf(-2.f, r2, 1.f);
        float u3 = fmaf(-2.f, r3, 1.f);
        A0 = fmaf(fabsf(d0), u0, A0);
        A1 = fmaf(fabsf(d1), u1, A1);
        A2 = fmaf(fabsf(d2), u2, A2);
        A3 = fmaf(fabsf(d3), u3, A3);
    }
    float A = (A0 + A1) + (A2 + A3);

    // logits: g_j = max(-A*|alpha|/64, -100)   (sign(alpha) cancels exactly)
    float gl = fmaxf(-A * aa * (1.0f / 64.0f), -MAXR);

    float gm = gl;
    #pragma unroll
    for (int off = 32; off; off >>= 1) gm = fmaxf(gm, __shfl_xor(gm, off, 64));
    float ew  = exp2_fast((gl - gm) * LOG2E);
    float den = ew, num = xj * ew;
    #pragma unroll
    for (int off = 32; off; off >>= 1) {
        den += __shfl_xor(den, off, 64);
        num += __shfl_xor(num, off, 64);
    }
    if (lane == 0) out[p] = num * rcp_fast(den);   // den >= 1
}

extern "C" void kernel_launch(void* const* d_in, const int* in_sizes, int n_in,
                              void* d_out, int out_size, void* d_ws, size_t ws_size,
                              hipStream_t stream) {
    const float* x      = (const float*)d_in[0];   // (4,64,64,64)
    const float* conv_w = (const float*)d_in[1];   // (2,64,3,3)
    const float* conv_b = (const float*)d_in[2];   // (2,)
    float* out   = (float*)d_out;                  // (4,1,64,64)

    float* xT    = (float*)d_ws;                   // 1048576 floats (4 MB)
    float* alpha = xT + 1048576;                   // 16384 floats
    float* beta  = alpha + 16384;                  // 16384 floats

    prep<<<256, 256, 0, stream>>>(x, conv_w, conv_b, xT, alpha, beta);
    pairwise<<<4096, 256, 0, stream>>>(xT, alpha, beta, out);
}

// Round 7
// 84.888 us; speedup vs baseline: 1.1231x; 1.0887x over previous
//
#include <hip/hip_runtime.h>
#include <math.h>

#define MAXR 100.0f
#define LOG2E 1.4426950408889634f
// Fixed shapes: B=4, C=64, H=64, W=64; conv (2,64,3,3) OIHW, SAME.

__device__ __forceinline__ float bcast_lane(float v, int i) {
    return __int_as_float(__builtin_amdgcn_readlane(__float_as_int(v), i));
}
__device__ __forceinline__ float exp2_fast(float x) { return __builtin_amdgcn_exp2f(x); }
__device__ __forceinline__ float rcp_fast(float x)  { return __builtin_amdgcn_rcpf(x); }

__device__ __forceinline__ float tanh_fast(float s) {
    // tanh(s) = sign(s) * (1 - 2/(e^{2|s|}+1)); E=inf -> t=1 exactly
    float E = exp2_fast(2.0f * LOG2E * fabsf(s));
    float t = fmaf(-2.0f, rcp_fast(E + 1.0f), 1.0f);
    return copysignf(t, s);
}

// Single fused kernel, minimal structure. 4096 blocks x 256 threads (4 waves).
// Block = 4 consecutive-w pixels (same b,h); ONE pixel per wave; lane = channel.
// LDS: only the 64c x 3r x 6w conv window (4.9 KB). Pairwise broadcast via
// v_readlane (VALU), conv weights straight from global (L2-hot).
__global__ __launch_bounds__(256) void dsf_fused(const float* __restrict__ x,
                                                 const float* __restrict__ wg,
                                                 const float* __restrict__ bias,
                                                 float* __restrict__ out) {
    __shared__ float xs[64 * 19];       // [c][r*6+wt], stride 19 (gcd(19,32)=1)

    const int tid  = threadIdx.x;
    const int lane = tid & 63;
    const int wave = tid >> 6;

    const int p0 = blockIdx.x * 4;      // b*4096 + h*64 + w0, w0 multiple of 4
    const int b  = p0 >> 12;
    const int h  = (p0 >> 6) & 63;
    const int w0 = p0 & 63;

    // per-lane conv weights (channel = lane): 18 dwords from L2 (reused chip-wide)
    float wr0[9], wr1[9];
    #pragma unroll
    for (int k = 0; k < 9; ++k) {
        wr0[k] = wg[lane * 9 + k];
        wr1[k] = wg[576 + lane * 9 + k];
    }
    const float b0 = bias[0], b1 = bias[1];

    // stage x[b, :, h-1:h+2, w0-1:w0+4] zero-padded into xs
    const float* xbase = x + b * 262144;
    for (int e = tid; e < 1152; e += 256) {
        int c   = e / 18;
        int rem = e - c * 18;
        int r   = rem / 6;
        int wt  = rem - r * 6;
        int hh  = h + r - 1;
        int ww  = w0 - 1 + wt;
        float v = 0.f;
        if (hh >= 0 && hh < 64 && ww >= 0 && ww < 64)
            v = xbase[c * 4096 + hh * 64 + ww];
        xs[c * 19 + rem] = v;
    }
    __syncthreads();

    // ---- conv for this wave's pixel: lane sums its channel's 9 taps ----
    const float* xc = xs + lane * 19;
    float a0 = 0.f, a1 = 0.f;
    #pragma unroll
    for (int r = 0; r < 3; ++r) {
        #pragma unroll
        for (int t = 0; t < 3; ++t) {
            float xv = xc[r * 6 + wave + t];
            a0 = fmaf(xv, wr0[r * 3 + t], a0);
            a1 = fmaf(xv, wr1[r * 3 + t], a1);
        }
    }
    #pragma unroll
    for (int off = 32; off; off >>= 1) {
        a0 += __shfl_xor(a0, off, 64);
        a1 += __shfl_xor(a1, off, 64);
    }
    const float al = MAXR * tanh_fast(a0 + b0);    // alpha (wave-uniform)
    const float be = MAXR * tanh_fast(a1 + b1);    // beta
    const float aa = fabsf(al);
    const float c2 = 2.0f * LOG2E * aa;            // t = 1 - 2/(2^(c2*|d|)+1)

    const float xj = xc[6 + wave + 1];             // x[b, lane, h, w0+wave]

    // ---- pairwise: A_j = sum_i |be*x_i - x_j| * tanh(aa*|...|), 4 chains ----
    float A0 = 0.f, A1 = 0.f, A2 = 0.f, A3 = 0.f;
    #pragma unroll
    for (int i = 0; i < 16; ++i) {
        float s0 = bcast_lane(xj, i);
        float s1 = bcast_lane(xj, i + 16);
        float s2 = bcast_lane(xj, i + 32);
        float s3 = bcast_lane(xj, i + 48);
        float d0 = fmaf(be, s0, -xj);
        float d1 = fmaf(be, s1, -xj);
        float d2 = fmaf(be, s2, -xj);
        float d3 = fmaf(be, s3, -xj);
        float E0 = exp2_fast(c2 * fabsf(d0));
        float E1 = exp2_fast(c2 * fabsf(d1));
        float E2 = exp2_fast(c2 * fabsf(d2));
        float E3 = exp2_fast(c2 * fabsf(d3));
        float r0 = rcp_fast(E0 + 1.f);
        float r1 = rcp_fast(E1 + 1.f);
        float r2 = rcp_fast(E2 + 1.f);
        float r3 = rcp_fast(E3 + 1.f);
        float u0 = fmaf(-2.f, r0, 1.f);
        float u1 = fmaf(-2.f, r1, 1.f);
        float u2 = fmaf(-2.f, r2, 1.f);
        float u3 = fmaf(-2.f, r3, 1.f);
        A0 = fmaf(fabsf(d0), u0, A0);
        A1 = fmaf(fabsf(d1), u1, A1);
        A2 = fmaf(fabsf(d2), u2, A2);
        A3 = fmaf(fabsf(d3), u3, A3);
    }
    float A = (A0 + A1) + (A2 + A3);

    // logits: g_j = max(-A*|alpha|/64, -100)  (sign(alpha) cancels exactly)
    float gl = fmaxf(-A * aa * (1.0f / 64.0f), -MAXR);

    float gm = gl;
    #pragma unroll
    for (int off = 32; off; off >>= 1) gm = fmaxf(gm, __shfl_xor(gm, off, 64));
    float ew  = exp2_fast((gl - gm) * LOG2E);
    float den = ew, num = xj * ew;
    #pragma unroll
    for (int off = 32; off; off >>= 1) {
        den += __shfl_xor(den, off, 64);
        num += __shfl_xor(num, off, 64);
    }
    if (lane == 0) out[p0 + wave] = num * rcp_fast(den);   // den >= 1
}

extern "C" void kernel_launch(void* const* d_in, const int* in_sizes, int n_in,
                              void* d_out, int out_size, void* d_ws, size_t ws_size,
                              hipStream_t stream) {
    const float* x      = (const float*)d_in[0];   // (4,64,64,64)
    const float* conv_w = (const float*)d_in[1];   // (2,64,3,3)
    const float* conv_b = (const float*)d_in[2];   // (2,)
    float* out = (float*)d_out;                    // (4,1,64,64)
    (void)d_ws; (void)ws_size;

    dsf_fused<<<4096, 256, 0, stream>>>(x, conv_w, conv_b, out);
}